// Round 10
// baseline (47.238 us; speedup 1.0000x reference)
//
#include <hip/hip_runtime.h>
#include <hip/hip_bf16.h>

#define NN 256
#define VC 32
#define FD 128

typedef unsigned int uint32;
typedef unsigned short u16;
typedef __attribute__((ext_vector_type(8))) short bf16x8;
typedef __attribute__((ext_vector_type(4))) float f32x4;

__device__ __forceinline__ float selu_f(float x) {
    const float lam = 1.0507009873554805f;
    const float la  = 1.7580993408473766f;
    return x > 0.f ? lam * x : la * (__expf(x) - 1.f);
}

__device__ __forceinline__ u16 f32_to_bf16_rne(float f) {
    uint32 u = __float_as_uint(f);
    uint32 r = (u + 0x7fffu + ((u >> 16) & 1u)) >> 16;
    return (u16)r;
}

__device__ __forceinline__ float bf16_to_f32(u16 h) {
    return __uint_as_float(((uint32)h) << 16);
}

struct Params {
    const float *pos, *feat, *We1, *be1, *We2, *be2, *Wq, *Wk, *Wv, *Wvec,
                *Wmix, *M1, *bm1, *M2, *bm2, *M3, *bm3;
    float *A, *Bf;
    u16 *kqb, *w1b, *we2b, *wvb, *fvtH, *fvtL, *ptH, *ptL;
    float *lgg2;
    u16 *cfg2;
    float *inv, *vec4;
    float *out0, *out1;
};

// ---------------------------------------------------------------- K1: node precompute (512 blocks)
__global__ __launch_bounds__(256) void k1_pre(Params P)
{
    __shared__ float fl[FD];
    __shared__ float ql[FD];
    const int vb = blockIdx.x;
    const int t = threadIdx.x;
    if (vb < 256) {
        const int n = vb;
        {   // weight repack spread (1 elem/thread over first 88 blocks)
            const int gid = n*256 + t;
            if (gid < 16384) {
                const int c = gid >> 8, k = gid & 255;
                P.w1b[gid] = f32_to_bf16_rne(P.We1[(256 + k)*64 + c]);
            } else if (gid < 20480) {
                const int o = gid - 16384;
                const int c = o >> 6, k = o & 63;
                P.we2b[o] = f32_to_bf16_rne(P.We2[k*64 + c]);
            } else if (gid < 22528) {
                const int o = gid - 20480;
                const int v = o >> 6, k = o & 63;
                P.wvb[o] = f32_to_bf16_rne(P.Wvec[k*32 + v]);
            }
        }
        if (t < FD) fl[t] = P.feat[n*FD + t];
        __syncthreads();
        if (t < 64) {
            float a0 = 0.f, a1 = 0.f;
            for (int i = 0; i < FD; i += 2) {
                a0 = fmaf(fl[i],   P.We1[i*64 + t],     a0);
                a1 = fmaf(fl[i+1], P.We1[(i+1)*64 + t], a1);
            }
            P.A[n*64 + t] = a0 + a1;
        } else if (t < 128) {
            const int j = t - 64;
            float a0 = P.be1[j], a1 = 0.f;
            for (int i = 0; i < FD; i += 2) {
                a0 = fmaf(fl[i],   P.We1[(FD+i)*64 + j],   a0);
                a1 = fmaf(fl[i+1], P.We1[(FD+i+1)*64 + j], a1);
            }
            P.Bf[n*64 + j] = a0 + a1;
        } else {
            const int j = t - 128;
            float a0 = 0.f, a1 = 0.f;
            for (int i = 0; i < FD; i += 2) {
                a0 = fmaf(fl[i],   P.Wq[i*FD + j],     a0);
                a1 = fmaf(fl[i+1], P.Wq[(i+1)*FD + j], a1);
            }
            ql[j] = (a0 + a1) * 0.25f;   // fold 1/sqrt(DH)
        }
        if (t < 8)  P.lgg2[n*2048 + t*256 + n] = -1e30f;       // self-edge excluded
        if (t < 32) P.cfg2[(size_t)n*8192 + t*256 + n] = 0;
        __syncthreads();
        for (int o = t; o < 512; o += 256) {   // kqb[n][h][j]
            const int h = o >> 6, j = o & 63;
            float a = 0.f;
            #pragma unroll
            for (int d = 0; d < 16; ++d)
                a = fmaf(P.Wk[j*FD + h*16 + d], ql[h*16 + d], a);
            P.kqb[n*512 + o] = f32_to_bf16_rne(a);
        }
    } else {
        const int n = vb - 256;
        if (t < FD) fl[t] = P.feat[n*FD + t];
        __syncthreads();
        if (t < FD) {
            float a0 = 0.f, a1 = 0.f;
            for (int i = 0; i < FD; i += 2) {
                a0 = fmaf(fl[i],   P.Wv[i*FD + t],     a0);
                a1 = fmaf(fl[i+1], P.Wv[(i+1)*FD + t], a1);
            }
            const float a = a0 + a1;
            const u16 hi = f32_to_bf16_rne(a);
            const u16 lo = f32_to_bf16_rne(a - bf16_to_f32(hi));
            P.fvtH[t*256 + n] = hi;
            P.fvtL[t*256 + n] = lo;
            const int v = t >> 2, c = t & 3;
            const float val = (c < 3) ? P.pos[(n*VC + v)*3 + c] : 1.0f;
            const u16 phi = f32_to_bf16_rne(val);
            const u16 plo = f32_to_bf16_rne(val - bf16_to_f32(phi));
            P.ptH[(v*4+c)*256 + n] = phi;
            P.ptL[(v*4+c)*256 + n] = plo;
        }
    }
}

// ---------------------------------------------------------------- K2: edge pipeline (MFMA), 512 blocks
__global__ __launch_bounds__(256) void k2_edge(Params P)
{
    __shared__ u16 rad[8192];       // [32e][32v][8b] bf16, xor-swizzled (16KB)
    __shared__ u16 h1b[2048];
    __shared__ u16 h2b[2048];
    __shared__ float invl[1056];

    const int t = threadIdx.x;
    const int wave = t >> 6, l = t & 63;
    const int li = l & 15, q = l >> 4;
    const int mh = wave >> 1, eh = wave & 1;
    const int r = blockIdx.x >> 1, tpart = blockIdx.x & 1;
    const int e = eh*16 + li;
    const int swz16 = (e & 7) << 3;

    bf16x8 w1A[2][8];
    #pragma unroll
    for (int mt = 0; mt < 2; ++mt) {
        const int c = mh*32 + mt*16 + li;
        #pragma unroll
        for (int kb = 0; kb < 8; ++kb)
            w1A[mt][kb] = *(const bf16x8*)(P.w1b + c*256 + kb*32 + q*8);
    }
    bf16x8 we2A[2][2];
    #pragma unroll
    for (int mt = 0; mt < 2; ++mt) {
        const int c2 = mh*32 + mt*16 + li;
        #pragma unroll
        for (int kb = 0; kb < 2; ++kb)
            we2A[mt][kb] = *(const bf16x8*)(P.we2b + c2*64 + kb*32 + q*8);
    }
    bf16x8 wvA[2];
    {
        const int v = mh*16 + li;
        #pragma unroll
        for (int kb = 0; kb < 2; ++kb)
            wvA[kb] = *(const bf16x8*)(P.wvb + v*64 + kb*32 + q*8);
    }
    bf16x8 kqA[2];
    if (li < 8) {
        #pragma unroll
        for (int kb = 0; kb < 2; ++kb)
            kqA[kb] = *(const bf16x8*)(P.kqb + r*512 + li*64 + kb*32 + q*8);
    } else {
        #pragma unroll
        for (int kb = 0; kb < 2; ++kb)
            #pragma unroll
            for (int j = 0; j < 8; ++j) kqA[kb][j] = 0;
    }
    float bfreg[2][4], be2reg[2][4];
    #pragma unroll
    for (int mt = 0; mt < 2; ++mt)
        #pragma unroll
        for (int rg = 0; rg < 4; ++rg) {
            const int c = mh*32 + mt*16 + q*4 + rg;
            bfreg[mt][rg] = P.Bf[r*64 + c];
            be2reg[mt][rg] = P.be2[c];
        }

    for (int it = 0; it < 4; ++it) {
        const int s0 = (tpart*4 + it) * 32;
        const int sp = s0 + e;
        int s = sp + (sp >= r ? 1 : 0); if (s > 255) s = 255;
        __syncthreads();

        float As[2][4];
        #pragma unroll
        for (int mt = 0; mt < 2; ++mt)
            #pragma unroll
            for (int rg = 0; rg < 4; ++rg)
                As[mt][rg] = P.A[s*64 + mh*32 + mt*16 + q*4 + rg];

        {   // radial basis -> swizzled LDS
            const int ep = t & 31, vg = t >> 5;
            const int spp = s0 + ep;
            int sv = spp + (spp >= r ? 1 : 0); if (sv > 255) sv = 255;
            #pragma unroll
            for (int kk = 0; kk < 4; ++kk) {
                const int v = vg*4 + kk;
                const float* ps = P.pos + (sv*VC + v)*3;
                const float* pr = P.pos + (r*VC + v)*3;
                const float dx = ps[0]-pr[0], dy = ps[1]-pr[1], dz = ps[2]-pr[2];
                const float d2 = fmaf(dx,dx,fmaf(dy,dy,dz*dz)) + 1e-18f;
                const float len = sqrtf(d2);
                invl[ep*33 + v] = rsqrtf(d2);
                const float x = fmaxf(len, 1e-6f);
                const float tt2 = 2.f - 0.4f*len;
                const float env = tt2 > 0.f ? 1.9784655248401538f * __expf(-1.f/tt2) : 0.f;
                const float coefc = 0.6324555320336759f * env / x;
                float s_cur, c1;
                __sincosf(0.6283185307179586f * x, &s_cur, &c1);
                const float c2x = 2.f * c1;
                float s_prev = 0.f;
                union { uint4 u4; u16 us[8]; } pk;
                #pragma unroll
                for (int bb = 0; bb < 8; ++bb) {
                    pk.us[bb] = f32_to_bf16_rne(coefc * s_cur);
                    const float s_next = fmaf(c2x, s_cur, -s_prev);
                    s_prev = s_cur; s_cur = s_next;
                }
                *(uint4*)((char*)rad + ((ep*512 + v*16) ^ ((ep & 15) << 4))) = pk.u4;
            }
        }
        __syncthreads();

        f32x4 d1[2] = {{0.f,0.f,0.f,0.f},{0.f,0.f,0.f,0.f}};
        #pragma unroll
        for (int kb = 0; kb < 8; ++kb) {
            const bf16x8 rf = *(const bf16x8*)((const char*)rad +
                                ((e*512 + (kb*4+q)*16) ^ ((e & 15) << 4)));
            d1[0] = __builtin_amdgcn_mfma_f32_16x16x32_bf16(w1A[0][kb], rf, d1[0], 0, 0, 0);
            d1[1] = __builtin_amdgcn_mfma_f32_16x16x32_bf16(w1A[1][kb], rf, d1[1], 0, 0, 0);
        }
        #pragma unroll
        for (int mt = 0; mt < 2; ++mt) {
            const int c0 = mh*32 + mt*16 + q*4;
            const u16 p0 = f32_to_bf16_rne(selu_f(d1[mt][0] + As[mt][0] + bfreg[mt][0]));
            const u16 p1 = f32_to_bf16_rne(selu_f(d1[mt][1] + As[mt][1] + bfreg[mt][1]));
            const u16 p2 = f32_to_bf16_rne(selu_f(d1[mt][2] + As[mt][2] + bfreg[mt][2]));
            const u16 p3 = f32_to_bf16_rne(selu_f(d1[mt][3] + As[mt][3] + bfreg[mt][3]));
            *(uint32*)&h1b[e*64 + ((c0)     ^ swz16)] = (uint32)p0 | ((uint32)p1 << 16);
            *(uint32*)&h1b[e*64 + ((c0 + 2) ^ swz16)] = (uint32)p2 | ((uint32)p3 << 16);
        }
        __syncthreads();

        f32x4 d2[2] = {{0.f,0.f,0.f,0.f},{0.f,0.f,0.f,0.f}};
        #pragma unroll
        for (int kb = 0; kb < 2; ++kb) {
            const bf16x8 hb = *(const bf16x8*)&h1b[e*64 + ((kb*32 + q*8) ^ swz16)];
            d2[0] = __builtin_amdgcn_mfma_f32_16x16x32_bf16(we2A[0][kb], hb, d2[0], 0, 0, 0);
            d2[1] = __builtin_amdgcn_mfma_f32_16x16x32_bf16(we2A[1][kb], hb, d2[1], 0, 0, 0);
        }
        #pragma unroll
        for (int mt = 0; mt < 2; ++mt) {
            const int c0 = mh*32 + mt*16 + q*4;
            const u16 p0 = f32_to_bf16_rne(selu_f(d2[mt][0] + be2reg[mt][0]));
            const u16 p1 = f32_to_bf16_rne(selu_f(d2[mt][1] + be2reg[mt][1]));
            const u16 p2 = f32_to_bf16_rne(selu_f(d2[mt][2] + be2reg[mt][2]));
            const u16 p3 = f32_to_bf16_rne(selu_f(d2[mt][3] + be2reg[mt][3]));
            *(uint32*)&h2b[e*64 + ((c0)     ^ swz16)] = (uint32)p0 | ((uint32)p1 << 16);
            *(uint32*)&h2b[e*64 + ((c0 + 2) ^ swz16)] = (uint32)p2 | ((uint32)p3 << 16);
        }
        __syncthreads();

        f32x4 d3 = {0.f,0.f,0.f,0.f};
        f32x4 dl = {0.f,0.f,0.f,0.f};
        #pragma unroll
        for (int kb = 0; kb < 2; ++kb) {
            const bf16x8 hb = *(const bf16x8*)&h2b[e*64 + ((kb*32 + q*8) ^ swz16)];
            d3 = __builtin_amdgcn_mfma_f32_16x16x32_bf16(wvA[kb], hb, d3, 0, 0, 0);
            if (mh == 0)
                dl = __builtin_amdgcn_mfma_f32_16x16x32_bf16(kqA[kb], hb, dl, 0, 0, 0);
        }
        if (sp < 255) {
            #pragma unroll
            for (int rg = 0; rg < 4; ++rg) {
                const int v = mh*16 + q*4 + rg;
                P.cfg2[(size_t)r*8192 + v*256 + s] =
                    f32_to_bf16_rne(d3[rg] * 1.7320508075688772f * invl[e*33 + v]);
            }
            if (mh == 0 && q < 2) {
                #pragma unroll
                for (int rg = 0; rg < 4; ++rg)
                    P.lgg2[(size_t)r*2048 + (q*4+rg)*256 + s] = dl[rg];
            }
        }
    }
}

// ---------------------------------------------------------------- K3b: MFMA aggregations + fused softmax (640 x 64)
// LDS-staged: logits (and coeffs) loaded coalesced into LDS, fragments read from LDS.
__global__ __launch_bounds__(64) void k3b_agg(Params P)
{
    __shared__ float lgs[16*260];   // [row][k], pad->260 (16B-aligned rows, balanced banks)
    __shared__ u16   cfs[16*264];   // [row][k] bf16, pad->264
    const int l = threadIdx.x, li = l & 15, q = l >> 4;
    const int task = blockIdx.x;
    int r0, hh, v = 0;
    const bool isInv = (task < 128);
    if (isInv) { hh = task >> 4; r0 = (task & 15) * 16; }
    else { const int b2 = task - 128; v = b2 >> 4; r0 = (b2 & 15) * 16; hh = v >> 2; }

    // ---- coalesced stage: 16 rows x 256 f32 logits
    for (int idx = l; idx < 1024; idx += 64) {
        const int row = idx >> 6, c4 = idx & 63;
        *(float4*)&lgs[row*260 + c4*4] =
            *(const float4*)(P.lgg2 + (size_t)(r0+row)*2048 + hh*256 + c4*4);
    }
    if (!isInv) {
        for (int idx = l; idx < 512; idx += 64) {
            const int row = idx >> 5, c8 = idx & 31;
            *(uint4*)&cfs[row*264 + c8*8] =
                *(const uint4*)(P.cfg2 + (size_t)(r0+row)*8192 + v*256 + c8*8);
        }
    }

    if (isInv) {
        bf16x8 fH[8], fL[8];
        #pragma unroll
        for (int kb = 0; kb < 8; ++kb) {
            fH[kb] = *(const bf16x8*)(P.fvtH + (hh*16+li)*256 + kb*32 + q*8);
            fL[kb] = *(const bf16x8*)(P.fvtL + (hh*16+li)*256 + kb*32 + q*8);
        }
        __syncthreads();
        const float* lrow = lgs + li*260;
        float mx = -3.0e38f;
        #pragma unroll
        for (int kb = 0; kb < 8; ++kb) {
            const float4 g0 = *(const float4*)(lrow + kb*32 + q*8);
            const float4 g1 = *(const float4*)(lrow + kb*32 + q*8 + 4);
            mx = fmaxf(mx, fmaxf(fmaxf(g0.x,g0.y), fmaxf(g0.z,g0.w)));
            mx = fmaxf(mx, fmaxf(fmaxf(g1.x,g1.y), fmaxf(g1.z,g1.w)));
        }
        mx = fmaxf(mx, __shfl_xor(mx, 16));
        mx = fmaxf(mx, __shfl_xor(mx, 32));
        float ssum = 0.f;
        f32x4 Ch = {0.f,0.f,0.f,0.f};
        f32x4 Cl = {0.f,0.f,0.f,0.f};
        #pragma unroll
        for (int kb = 0; kb < 8; ++kb) {
            const float4 g0 = *(const float4*)(lrow + kb*32 + q*8);
            const float4 g1 = *(const float4*)(lrow + kb*32 + q*8 + 4);
            float ev[8];
            ev[0]=__expf(g0.x-mx); ev[1]=__expf(g0.y-mx); ev[2]=__expf(g0.z-mx); ev[3]=__expf(g0.w-mx);
            ev[4]=__expf(g1.x-mx); ev[5]=__expf(g1.y-mx); ev[6]=__expf(g1.z-mx); ev[7]=__expf(g1.w-mx);
            bf16x8 a;
            #pragma unroll
            for (int j = 0; j < 8; ++j) { ssum += ev[j]; a[j] = (short)f32_to_bf16_rne(ev[j]); }
            Ch = __builtin_amdgcn_mfma_f32_16x16x32_bf16(a, fH[kb], Ch, 0, 0, 0);
            Cl = __builtin_amdgcn_mfma_f32_16x16x32_bf16(a, fL[kb], Cl, 0, 0, 0);
        }
        ssum += __shfl_xor(ssum, 16);
        ssum += __shfl_xor(ssum, 32);
        #pragma unroll
        for (int rg = 0; rg < 4; ++rg) {
            const float d = __shfl(ssum, q*4 + rg);
            P.inv[(r0 + q*4 + rg)*128 + hh*16 + li] = (Ch[rg] + Cl[rg]) / (d + 1e-12f);
        }
    } else {
        bf16x8 pH[8], pL[8];
        #pragma unroll
        for (int kb = 0; kb < 8; ++kb) {
            if (li < 4) {
                pH[kb] = *(const bf16x8*)(P.ptH + (v*4+li)*256 + kb*32 + q*8);
                pL[kb] = *(const bf16x8*)(P.ptL + (v*4+li)*256 + kb*32 + q*8);
            } else {
                #pragma unroll
                for (int j = 0; j < 8; ++j) { pH[kb][j] = 0; pL[kb][j] = 0; }
            }
        }
        __syncthreads();
        const float* lrow = lgs + li*260;
        const u16*   crow = cfs + li*264;
        float mx = -3.0e38f;
        #pragma unroll
        for (int kb = 0; kb < 8; ++kb) {
            const float4 g0 = *(const float4*)(lrow + kb*32 + q*8);
            const float4 g1 = *(const float4*)(lrow + kb*32 + q*8 + 4);
            mx = fmaxf(mx, fmaxf(fmaxf(g0.x,g0.y), fmaxf(g0.z,g0.w)));
            mx = fmaxf(mx, fmaxf(fmaxf(g1.x,g1.y), fmaxf(g1.z,g1.w)));
        }
        mx = fmaxf(mx, __shfl_xor(mx, 16));
        mx = fmaxf(mx, __shfl_xor(mx, 32));
        float ssum = 0.f;
        f32x4 Ch = {0.f,0.f,0.f,0.f};
        f32x4 Cl = {0.f,0.f,0.f,0.f};
        #pragma unroll
        for (int kb = 0; kb < 8; ++kb) {
            const float4 g0 = *(const float4*)(lrow + kb*32 + q*8);
            const float4 g1 = *(const float4*)(lrow + kb*32 + q*8 + 4);
            const bf16x8 cf8 = *(const bf16x8*)(crow + kb*32 + q*8);
            float ev[8];
            ev[0]=__expf(g0.x-mx); ev[1]=__expf(g0.y-mx); ev[2]=__expf(g0.z-mx); ev[3]=__expf(g0.w-mx);
            ev[4]=__expf(g1.x-mx); ev[5]=__expf(g1.y-mx); ev[6]=__expf(g1.z-mx); ev[7]=__expf(g1.w-mx);
            bf16x8 a;
            #pragma unroll
            for (int j = 0; j < 8; ++j) {
                ssum += ev[j];
                a[j] = (short)f32_to_bf16_rne(ev[j] * bf16_to_f32((u16)cf8[j]));
            }
            Ch = __builtin_amdgcn_mfma_f32_16x16x32_bf16(a, pH[kb], Ch, 0, 0, 0);
            Cl = __builtin_amdgcn_mfma_f32_16x16x32_bf16(a, pL[kb], Cl, 0, 0, 0);
        }
        ssum += __shfl_xor(ssum, 16);
        ssum += __shfl_xor(ssum, 32);
        #pragma unroll
        for (int rg = 0; rg < 4; ++rg) {
            const float d = __shfl(ssum, q*4 + rg);
            if (li < 4)
                P.vec4[(r0 + q*4 + rg)*128 + v*4 + li] = (Ch[rg] + Cl[rg]) / (d + 1e-12f);
        }
    }
}

// ---------------------------------------------------------------- K3c: node MLP + vec combine (1 node/block, 256 thr)
__global__ __launch_bounds__(256) void k3c_out(Params P)
{
    __shared__ float part[4][64];
    __shared__ float inva[128];
    __shared__ float vec4s[128];
    __shared__ float pos96[96];
    __shared__ float vecl[96];
    __shared__ float hi1[64];
    __shared__ float hi2[64];
    const int r = blockIdx.x;
    const int t = threadIdx.x;
    if (t < 128) inva[t] = P.inv[r*128 + t];
    else         vec4s[t-128] = P.vec4[r*128 + (t-128)];
    if (t < 96)  pos96[t] = P.pos[r*96 + t];
    __syncthreads();
    if (t < 96) {
        const int v = t / 3, c = t - v*3;
        vecl[t] = vec4s[v*4 + c] - vec4s[v*4 + 3] * pos96[t];
    }
    {   // stage1 partials: 4-way K-split
        const int f = t & 63, g = t >> 6;
        const int k0 = g*32;
        float acc = 0.f;
        #pragma unroll 8
        for (int k = k0; k < k0 + 32; ++k)
            acc = fmaf(inva[k], P.M1[k*64 + f], acc);
        part[g][f] = acc;
    }
    __syncthreads();
    if (t < 64) {
        const float a1 = P.bm1[t] + part[0][t] + part[1][t] + part[2][t] + part[3][t];
        hi1[t] = selu_f(a1);
    }
    __syncthreads();
    if (t < 64) {
        float a0 = P.bm2[t], a1 = 0.f;
        #pragma unroll 8
        for (int k = 0; k < 64; k += 2) {
            a0 = fmaf(hi1[k],   P.M2[k*64 + t],     a0);
            a1 = fmaf(hi1[k+1], P.M2[(k+1)*64 + t], a1);
        }
        hi2[t] = selu_f(a0 + a1);
    }
    __syncthreads();
    if (t < 128) {
        float a0 = P.bm3[t], a1 = 0.f;
        #pragma unroll 8
        for (int k = 0; k < 64; k += 2) {
            a0 = fmaf(hi2[k],   P.M3[k*128 + t],     a0);
            a1 = fmaf(hi2[k+1], P.M3[(k+1)*128 + t], a1);
        }
        P.out1[r*128 + t] = a0 + a1 + P.feat[r*128 + t];
    } else if (t < 224) {
        const int o = t - 128;
        const int w = o / 3, c = o - w*3;
        float a = 0.f;
        #pragma unroll
        for (int v = 0; v < 32; ++v)
            a = fmaf(vecl[v*3 + c], P.Wmix[v*32 + w], a);
        P.out0[r*96 + o] = a + pos96[o];
    }
}

extern "C" void kernel_launch(void* const* d_in, const int* in_sizes, int n_in,
                              void* d_out, int out_size, void* d_ws, size_t ws_size,
                              hipStream_t stream)
{
    char* ws = (char*)d_ws;
    if (ws_size < (size_t)6991872) return;

    Params p;
    p.pos  = (const float*)d_in[0];
    p.feat = (const float*)d_in[1];
    p.We1  = (const float*)d_in[2];
    p.be1  = (const float*)d_in[3];
    p.We2  = (const float*)d_in[4];
    p.be2  = (const float*)d_in[5];
    p.Wq   = (const float*)d_in[6];
    p.Wk   = (const float*)d_in[7];
    p.Wv   = (const float*)d_in[8];
    p.Wvec = (const float*)d_in[9];
    p.Wmix = (const float*)d_in[10];
    p.M1   = (const float*)d_in[11];
    p.bm1  = (const float*)d_in[12];
    p.M2   = (const float*)d_in[13];
    p.bm2  = (const float*)d_in[14];
    p.M3   = (const float*)d_in[15];
    p.bm3  = (const float*)d_in[16];

    p.A    = (float*)(ws + 0);        // [256][64]
    p.Bf   = (float*)(ws + 65536);    // [256][64]
    p.kqb  = (u16*)(ws + 131072);     // [256][8][64]
    p.w1b  = (u16*)(ws + 393216);     // [64][256]
    p.we2b = (u16*)(ws + 425984);     // [64][64]
    p.wvb  = (u16*)(ws + 434176);     // [32][64]
    p.fvtH = (u16*)(ws + 438272);     // [128][256]
    p.fvtL = (u16*)(ws + 503808);
    p.ptH  = (u16*)(ws + 569344);     // [32][4][256]
    p.ptL  = (u16*)(ws + 634880);
    p.lgg2 = (float*)(ws + 700416);   // [256][8][256]
    p.cfg2 = (u16*)(ws + 2797568);    // [256][32][256]
    p.inv  = (float*)(ws + 0);        // overlay (A/Bf dead after K2)
    p.vec4 = (float*)(ws + 131072);   // overlay (kqb dead after K2)

    p.out0 = (float*)d_out;           // [256][32][3]
    p.out1 = p.out0 + NN*VC*3;        // [256][128]

    hipLaunchKernelGGL(k1_pre,  dim3(512), dim3(256), 0, stream, p);
    hipLaunchKernelGGL(k2_edge, dim3(512), dim3(256), 0, stream, p);
    hipLaunchKernelGGL(k3b_agg, dim3(640), dim3(64),  0, stream, p);
    hipLaunchKernelGGL(k3c_out, dim3(256), dim3(256), 0, stream, p);
}

// Round 11
// 45.578 us; speedup vs baseline: 1.0364x; 1.0364x over previous
//
#include <hip/hip_runtime.h>
#include <hip/hip_bf16.h>

#define NN 256
#define VC 32
#define FD 128

typedef unsigned int uint32;
typedef unsigned short u16;
typedef __attribute__((ext_vector_type(8))) short bf16x8;
typedef __attribute__((ext_vector_type(4))) float f32x4;

__device__ __forceinline__ float selu_f(float x) {
    const float lam = 1.0507009873554805f;
    const float la  = 1.7580993408473766f;
    return x > 0.f ? lam * x : la * (__expf(x) - 1.f);
}

__device__ __forceinline__ u16 f32_to_bf16_rne(float f) {
    uint32 u = __float_as_uint(f);
    uint32 r = (u + 0x7fffu + ((u >> 16) & 1u)) >> 16;
    return (u16)r;
}

__device__ __forceinline__ float bf16_to_f32(u16 h) {
    return __uint_as_float(((uint32)h) << 16);
}

struct Params {
    const float *pos, *feat, *We1, *be1, *We2, *be2, *Wq, *Wk, *Wv, *Wvec,
                *Wmix, *M1, *bm1, *M2, *bm2, *M3, *bm3;
    float *A, *Bf;
    u16 *kqb, *w1b, *we2b, *wvb, *fvtH, *fvtL, *ptH, *ptL;
    float *lgg2;
    u16 *cfg2;
    float *stats;            // [256 r][2 tpart][8 h][2] = (max, sumexp)
    float *inv, *vec4;
    float *out0, *out1;
};

// ---------------------------------------------------------------- K1: node precompute (512 blocks)
__global__ __launch_bounds__(256) void k1_pre(Params P)
{
    __shared__ float fl[FD];
    __shared__ float ql[FD];
    const int vb = blockIdx.x;
    const int t = threadIdx.x;
    if (vb < 256) {
        const int n = vb;
        {   // weight repack spread (1 elem/thread over first 88 blocks)
            const int gid = n*256 + t;
            if (gid < 16384) {
                const int c = gid >> 8, k = gid & 255;
                P.w1b[gid] = f32_to_bf16_rne(P.We1[(256 + k)*64 + c]);
            } else if (gid < 20480) {
                const int o = gid - 16384;
                const int c = o >> 6, k = o & 63;
                P.we2b[o] = f32_to_bf16_rne(P.We2[k*64 + c]);
            } else if (gid < 22528) {
                const int o = gid - 20480;
                const int v = o >> 6, k = o & 63;
                P.wvb[o] = f32_to_bf16_rne(P.Wvec[k*32 + v]);
            }
        }
        if (t < FD) fl[t] = P.feat[n*FD + t];
        __syncthreads();
        if (t < 64) {
            float a = 0.f;
            for (int i = 0; i < FD; ++i) a = fmaf(fl[i], P.We1[i*64 + t], a);
            P.A[n*64 + t] = a;
        } else if (t < 128) {
            const int j = t - 64;
            float a = P.be1[j];
            for (int i = 0; i < FD; ++i) a = fmaf(fl[i], P.We1[(FD+i)*64 + j], a);
            P.Bf[n*64 + j] = a;
        } else {
            const int j = t - 128;
            float a = 0.f;
            for (int i = 0; i < FD; ++i) a = fmaf(fl[i], P.Wq[i*FD + j], a);
            ql[j] = a * 0.25f;   // fold 1/sqrt(DH)
        }
        if (t < 8)  P.lgg2[n*2048 + t*256 + n] = -1e30f;       // self-edge excluded
        if (t < 32) P.cfg2[(size_t)n*8192 + t*256 + n] = 0;
        __syncthreads();
        for (int o = t; o < 512; o += 256) {   // kqb[n][h][j]
            const int h = o >> 6, j = o & 63;
            float a = 0.f;
            #pragma unroll
            for (int d = 0; d < 16; ++d)
                a = fmaf(P.Wk[j*FD + h*16 + d], ql[h*16 + d], a);
            P.kqb[n*512 + o] = f32_to_bf16_rne(a);
        }
    } else {
        const int n = vb - 256;
        if (t < FD) fl[t] = P.feat[n*FD + t];
        __syncthreads();
        if (t < FD) {
            float a = 0.f;
            for (int i = 0; i < FD; ++i) a = fmaf(fl[i], P.Wv[i*FD + t], a);
            const u16 hi = f32_to_bf16_rne(a);
            const u16 lo = f32_to_bf16_rne(a - bf16_to_f32(hi));
            P.fvtH[t*256 + n] = hi;
            P.fvtL[t*256 + n] = lo;
            const int v = t >> 2, c = t & 3;
            const float val = (c < 3) ? P.pos[(n*VC + v)*3 + c] : 1.0f;
            const u16 phi = f32_to_bf16_rne(val);
            const u16 plo = f32_to_bf16_rne(val - bf16_to_f32(phi));
            P.ptH[(v*4+c)*256 + n] = phi;
            P.ptL[(v*4+c)*256 + n] = plo;
        }
    }
}

// ---------------------------------------------------------------- K2: edge pipeline (MFMA) + softmax partials, 512 blocks
__global__ __launch_bounds__(256) void k2_edge(Params P)
{
    __shared__ u16 rad[8192];       // [32e][32v][8b] bf16, xor-swizzled (16KB)
    __shared__ u16 h1b[2048];
    __shared__ u16 h2b[2048];
    __shared__ float invl[1056];
    __shared__ float pm[2][8];      // softmax partial max  [eh][h]
    __shared__ float psv[2][8];     // softmax partial sum  [eh][h]

    const int t = threadIdx.x;
    const int wave = t >> 6, l = t & 63;
    const int li = l & 15, q = l >> 4;
    const int mh = wave >> 1, eh = wave & 1;
    const int r = blockIdx.x >> 1, tpart = blockIdx.x & 1;
    const int e = eh*16 + li;
    const int swz16 = (e & 7) << 3;

    bf16x8 w1A[2][8];
    #pragma unroll
    for (int mt = 0; mt < 2; ++mt) {
        const int c = mh*32 + mt*16 + li;
        #pragma unroll
        for (int kb = 0; kb < 8; ++kb)
            w1A[mt][kb] = *(const bf16x8*)(P.w1b + c*256 + kb*32 + q*8);
    }
    bf16x8 we2A[2][2];
    #pragma unroll
    for (int mt = 0; mt < 2; ++mt) {
        const int c2 = mh*32 + mt*16 + li;
        #pragma unroll
        for (int kb = 0; kb < 2; ++kb)
            we2A[mt][kb] = *(const bf16x8*)(P.we2b + c2*64 + kb*32 + q*8);
    }
    bf16x8 wvA[2];
    {
        const int v = mh*16 + li;
        #pragma unroll
        for (int kb = 0; kb < 2; ++kb)
            wvA[kb] = *(const bf16x8*)(P.wvb + v*64 + kb*32 + q*8);
    }
    bf16x8 kqA[2];
    if (li < 8) {
        #pragma unroll
        for (int kb = 0; kb < 2; ++kb)
            kqA[kb] = *(const bf16x8*)(P.kqb + r*512 + li*64 + kb*32 + q*8);
    } else {
        #pragma unroll
        for (int kb = 0; kb < 2; ++kb)
            #pragma unroll
            for (int j = 0; j < 8; ++j) kqA[kb][j] = 0;
    }
    float bfreg[2][4], be2reg[2][4];
    #pragma unroll
    for (int mt = 0; mt < 2; ++mt)
        #pragma unroll
        for (int rg = 0; rg < 4; ++rg) {
            const int c = mh*32 + mt*16 + q*4 + rg;
            bfreg[mt][rg] = P.Bf[r*64 + c];
            be2reg[mt][rg] = P.be2[c];
        }

    float m_run[4], s_run[4];
    #pragma unroll
    for (int rg = 0; rg < 4; ++rg) { m_run[rg] = -3.0e38f; s_run[rg] = 0.f; }

    for (int it = 0; it < 4; ++it) {
        const int s0 = (tpart*4 + it) * 32;
        const int sp = s0 + e;
        int s = sp + (sp >= r ? 1 : 0); if (s > 255) s = 255;
        __syncthreads();

        float As[2][4];
        #pragma unroll
        for (int mt = 0; mt < 2; ++mt)
            #pragma unroll
            for (int rg = 0; rg < 4; ++rg)
                As[mt][rg] = P.A[s*64 + mh*32 + mt*16 + q*4 + rg];

        {   // radial basis -> swizzled LDS
            const int ep = t & 31, vg = t >> 5;
            const int spp = s0 + ep;
            int sv = spp + (spp >= r ? 1 : 0); if (sv > 255) sv = 255;
            #pragma unroll
            for (int kk = 0; kk < 4; ++kk) {
                const int v = vg*4 + kk;
                const float* ps = P.pos + (sv*VC + v)*3;
                const float* pr = P.pos + (r*VC + v)*3;
                const float dx = ps[0]-pr[0], dy = ps[1]-pr[1], dz = ps[2]-pr[2];
                const float d2 = fmaf(dx,dx,fmaf(dy,dy,dz*dz)) + 1e-18f;
                const float len = sqrtf(d2);
                invl[ep*33 + v] = rsqrtf(d2);
                const float x = fmaxf(len, 1e-6f);
                const float tt2 = 2.f - 0.4f*len;
                const float env = tt2 > 0.f ? 1.9784655248401538f * __expf(-1.f/tt2) : 0.f;
                const float coefc = 0.6324555320336759f * env / x;
                float s_cur, c1;
                __sincosf(0.6283185307179586f * x, &s_cur, &c1);
                const float c2x = 2.f * c1;
                float s_prev = 0.f;
                union { uint4 u4; u16 us[8]; } pk;
                #pragma unroll
                for (int bb = 0; bb < 8; ++bb) {
                    pk.us[bb] = f32_to_bf16_rne(coefc * s_cur);
                    const float s_next = fmaf(c2x, s_cur, -s_prev);
                    s_prev = s_cur; s_cur = s_next;
                }
                *(uint4*)((char*)rad + ((ep*512 + v*16) ^ ((ep & 15) << 4))) = pk.u4;
            }
        }
        __syncthreads();

        f32x4 d1[2] = {{0.f,0.f,0.f,0.f},{0.f,0.f,0.f,0.f}};
        #pragma unroll
        for (int kb = 0; kb < 8; ++kb) {
            const bf16x8 rf = *(const bf16x8*)((const char*)rad +
                                ((e*512 + (kb*4+q)*16) ^ ((e & 15) << 4)));
            d1[0] = __builtin_amdgcn_mfma_f32_16x16x32_bf16(w1A[0][kb], rf, d1[0], 0, 0, 0);
            d1[1] = __builtin_amdgcn_mfma_f32_16x16x32_bf16(w1A[1][kb], rf, d1[1], 0, 0, 0);
        }
        #pragma unroll
        for (int mt = 0; mt < 2; ++mt) {
            const int c0 = mh*32 + mt*16 + q*4;
            const u16 p0 = f32_to_bf16_rne(selu_f(d1[mt][0] + As[mt][0] + bfreg[mt][0]));
            const u16 p1 = f32_to_bf16_rne(selu_f(d1[mt][1] + As[mt][1] + bfreg[mt][1]));
            const u16 p2 = f32_to_bf16_rne(selu_f(d1[mt][2] + As[mt][2] + bfreg[mt][2]));
            const u16 p3 = f32_to_bf16_rne(selu_f(d1[mt][3] + As[mt][3] + bfreg[mt][3]));
            *(uint32*)&h1b[e*64 + ((c0)     ^ swz16)] = (uint32)p0 | ((uint32)p1 << 16);
            *(uint32*)&h1b[e*64 + ((c0 + 2) ^ swz16)] = (uint32)p2 | ((uint32)p3 << 16);
        }
        __syncthreads();

        f32x4 d2[2] = {{0.f,0.f,0.f,0.f},{0.f,0.f,0.f,0.f}};
        #pragma unroll
        for (int kb = 0; kb < 2; ++kb) {
            const bf16x8 hb = *(const bf16x8*)&h1b[e*64 + ((kb*32 + q*8) ^ swz16)];
            d2[0] = __builtin_amdgcn_mfma_f32_16x16x32_bf16(we2A[0][kb], hb, d2[0], 0, 0, 0);
            d2[1] = __builtin_amdgcn_mfma_f32_16x16x32_bf16(we2A[1][kb], hb, d2[1], 0, 0, 0);
        }
        #pragma unroll
        for (int mt = 0; mt < 2; ++mt) {
            const int c0 = mh*32 + mt*16 + q*4;
            const u16 p0 = f32_to_bf16_rne(selu_f(d2[mt][0] + be2reg[mt][0]));
            const u16 p1 = f32_to_bf16_rne(selu_f(d2[mt][1] + be2reg[mt][1]));
            const u16 p2 = f32_to_bf16_rne(selu_f(d2[mt][2] + be2reg[mt][2]));
            const u16 p3 = f32_to_bf16_rne(selu_f(d2[mt][3] + be2reg[mt][3]));
            *(uint32*)&h2b[e*64 + ((c0)     ^ swz16)] = (uint32)p0 | ((uint32)p1 << 16);
            *(uint32*)&h2b[e*64 + ((c0 + 2) ^ swz16)] = (uint32)p2 | ((uint32)p3 << 16);
        }
        __syncthreads();

        f32x4 d3 = {0.f,0.f,0.f,0.f};
        f32x4 dl = {0.f,0.f,0.f,0.f};
        #pragma unroll
        for (int kb = 0; kb < 2; ++kb) {
            const bf16x8 hb = *(const bf16x8*)&h2b[e*64 + ((kb*32 + q*8) ^ swz16)];
            d3 = __builtin_amdgcn_mfma_f32_16x16x32_bf16(wvA[kb], hb, d3, 0, 0, 0);
            if (mh == 0)
                dl = __builtin_amdgcn_mfma_f32_16x16x32_bf16(kqA[kb], hb, dl, 0, 0, 0);
        }
        if (sp < 255) {
            #pragma unroll
            for (int rg = 0; rg < 4; ++rg) {
                const int v = mh*16 + q*4 + rg;
                P.cfg2[(size_t)r*8192 + v*256 + s] =
                    f32_to_bf16_rne(d3[rg] * 1.7320508075688772f * invl[e*33 + v]);
            }
            if (mh == 0 && q < 2) {
                #pragma unroll
                for (int rg = 0; rg < 4; ++rg) {
                    const float lgv = dl[rg];
                    P.lgg2[(size_t)r*2048 + (q*4+rg)*256 + s] = lgv;
                    // online softmax partial (this lane's sender only)
                    const float mo = m_run[rg];
                    if (lgv > mo) {
                        s_run[rg] = fmaf(s_run[rg], __expf(mo - lgv), 1.f);
                        m_run[rg] = lgv;
                    } else {
                        s_run[rg] += __expf(lgv - mo);
                    }
                }
            }
        }
    }

    // ---- combine softmax partials: reduce over li (in-wave), then over eh (LDS)
    if (mh == 0 && q < 2) {
        #pragma unroll
        for (int rg = 0; rg < 4; ++rg) {
            float m = m_run[rg], sv = s_run[rg];
            #pragma unroll
            for (int mask = 1; mask <= 8; mask <<= 1) {
                const float mo = __shfl_xor(m, mask);
                const float so = __shfl_xor(sv, mask);
                const float mn = fmaxf(m, mo);
                sv = sv*__expf(m - mn) + so*__expf(mo - mn);
                m = mn;
            }
            if (li == 0) { pm[eh][q*4+rg] = m; psv[eh][q*4+rg] = sv; }
        }
    }
    __syncthreads();
    if (t < 8) {
        const float m0 = pm[0][t], m1 = pm[1][t];
        const float s0v = psv[0][t], s1v = psv[1][t];
        const float m = fmaxf(m0, m1);
        const float sv = s0v*__expf(m0 - m) + s1v*__expf(m1 - m);
        P.stats[((r*2 + tpart)*8 + t)*2 + 0] = m;
        P.stats[((r*2 + tpart)*8 + t)*2 + 1] = sv;
    }
}

// ---------------------------------------------------------------- K3b: MFMA aggregations, single pass (640 x 64)
__global__ __launch_bounds__(64) void k3b_agg(Params P)
{
    const int l = threadIdx.x, li = l & 15, q = l >> 4;
    const int task = blockIdx.x;
    int r0, hh, v = 0;
    const bool isInv = (task < 128);
    if (isInv) { hh = task >> 4; r0 = (task & 15) * 16; }
    else { const int b2 = task - 128; v = b2 >> 4; r0 = (b2 & 15) * 16; hh = v >> 2; }

    // per-row softmax constants from k2 partials (row = r0+li)
    const float2 st0 = *(const float2*)&P.stats[(((r0+li)*2 + 0)*8 + hh)*2];
    const float2 st1 = *(const float2*)&P.stats[(((r0+li)*2 + 1)*8 + hh)*2];
    const float mx = fmaxf(st0.x, st1.x);
    const float den = st0.y*__expf(st0.x - mx) + st1.y*__expf(st1.x - mx);
    const float invden = 1.f / (den + 1e-12f);

    if (isInv) {
        bf16x8 fH[8], fL[8];
        #pragma unroll
        for (int kb = 0; kb < 8; ++kb) {
            fH[kb] = *(const bf16x8*)(P.fvtH + (hh*16+li)*256 + kb*32 + q*8);
            fL[kb] = *(const bf16x8*)(P.fvtL + (hh*16+li)*256 + kb*32 + q*8);
        }
        const float* lgr = P.lgg2 + (size_t)(r0+li)*2048 + hh*256;
        f32x4 Ch = {0.f,0.f,0.f,0.f};
        f32x4 Cl = {0.f,0.f,0.f,0.f};
        #pragma unroll
        for (int kb = 0; kb < 8; ++kb) {
            const float4 g0 = *(const float4*)(lgr + kb*32 + q*8);
            const float4 g1 = *(const float4*)(lgr + kb*32 + q*8 + 4);
            bf16x8 a;
            a[0] = (short)f32_to_bf16_rne(__expf(g0.x-mx));
            a[1] = (short)f32_to_bf16_rne(__expf(g0.y-mx));
            a[2] = (short)f32_to_bf16_rne(__expf(g0.z-mx));
            a[3] = (short)f32_to_bf16_rne(__expf(g0.w-mx));
            a[4] = (short)f32_to_bf16_rne(__expf(g1.x-mx));
            a[5] = (short)f32_to_bf16_rne(__expf(g1.y-mx));
            a[6] = (short)f32_to_bf16_rne(__expf(g1.z-mx));
            a[7] = (short)f32_to_bf16_rne(__expf(g1.w-mx));
            Ch = __builtin_amdgcn_mfma_f32_16x16x32_bf16(a, fH[kb], Ch, 0, 0, 0);
            Cl = __builtin_amdgcn_mfma_f32_16x16x32_bf16(a, fL[kb], Cl, 0, 0, 0);
        }
        #pragma unroll
        for (int rg = 0; rg < 4; ++rg) {
            const float d = __shfl(invden, q*4 + rg);
            P.inv[(r0 + q*4 + rg)*128 + hh*16 + li] = (Ch[rg] + Cl[rg]) * d;
        }
    } else {
        bf16x8 pH[8], pL[8];
        #pragma unroll
        for (int kb = 0; kb < 8; ++kb) {
            if (li < 4) {
                pH[kb] = *(const bf16x8*)(P.ptH + (v*4+li)*256 + kb*32 + q*8);
                pL[kb] = *(const bf16x8*)(P.ptL + (v*4+li)*256 + kb*32 + q*8);
            } else {
                #pragma unroll
                for (int j = 0; j < 8; ++j) { pH[kb][j] = 0; pL[kb][j] = 0; }
            }
        }
        const float* lgr = P.lgg2 + (size_t)(r0+li)*2048 + hh*256;
        const u16*  cfr = P.cfg2 + (size_t)(r0+li)*8192 + v*256;
        f32x4 Ch = {0.f,0.f,0.f,0.f};
        f32x4 Cl = {0.f,0.f,0.f,0.f};
        #pragma unroll
        for (int kb = 0; kb < 8; ++kb) {
            const float4 g0 = *(const float4*)(lgr + kb*32 + q*8);
            const float4 g1 = *(const float4*)(lgr + kb*32 + q*8 + 4);
            const bf16x8 cf8 = *(const bf16x8*)(cfr + kb*32 + q*8);
            bf16x8 a;
            a[0] = (short)f32_to_bf16_rne(__expf(g0.x-mx) * bf16_to_f32((u16)cf8[0]));
            a[1] = (short)f32_to_bf16_rne(__expf(g0.y-mx) * bf16_to_f32((u16)cf8[1]));
            a[2] = (short)f32_to_bf16_rne(__expf(g0.z-mx) * bf16_to_f32((u16)cf8[2]));
            a[3] = (short)f32_to_bf16_rne(__expf(g0.w-mx) * bf16_to_f32((u16)cf8[3]));
            a[4] = (short)f32_to_bf16_rne(__expf(g1.x-mx) * bf16_to_f32((u16)cf8[4]));
            a[5] = (short)f32_to_bf16_rne(__expf(g1.y-mx) * bf16_to_f32((u16)cf8[5]));
            a[6] = (short)f32_to_bf16_rne(__expf(g1.z-mx) * bf16_to_f32((u16)cf8[6]));
            a[7] = (short)f32_to_bf16_rne(__expf(g1.w-mx) * bf16_to_f32((u16)cf8[7]));
            Ch = __builtin_amdgcn_mfma_f32_16x16x32_bf16(a, pH[kb], Ch, 0, 0, 0);
            Cl = __builtin_amdgcn_mfma_f32_16x16x32_bf16(a, pL[kb], Cl, 0, 0, 0);
        }
        #pragma unroll
        for (int rg = 0; rg < 4; ++rg) {
            const float d = __shfl(invden, q*4 + rg);
            if (li < 4)
                P.vec4[(r0 + q*4 + rg)*128 + v*4 + li] = (Ch[rg] + Cl[rg]) * d;
        }
    }
}

// ---------------------------------------------------------------- K3c: node MLP + vec combine (1 node/block, 256 thr)
__global__ __launch_bounds__(256) void k3c_out(Params P)
{
    __shared__ float part[4][64];
    __shared__ float inva[128];
    __shared__ float vec4s[128];
    __shared__ float pos96[96];
    __shared__ float vecl[96];
    __shared__ float hi1[64];
    __shared__ float hi2[64];
    const int r = blockIdx.x;
    const int t = threadIdx.x;
    if (t < 128) inva[t] = P.inv[r*128 + t];
    else         vec4s[t-128] = P.vec4[r*128 + (t-128)];
    if (t < 96)  pos96[t] = P.pos[r*96 + t];
    __syncthreads();
    if (t < 96) {
        const int v = t / 3, c = t - v*3;
        vecl[t] = vec4s[v*4 + c] - vec4s[v*4 + 3] * pos96[t];
    }
    {   // stage1 partials: 4-way K-split
        const int f = t & 63, g = t >> 6;
        const int k0 = g*32;
        float acc = 0.f;
        #pragma unroll 8
        for (int k = k0; k < k0 + 32; ++k)
            acc = fmaf(inva[k], P.M1[k*64 + f], acc);
        part[g][f] = acc;
    }
    __syncthreads();
    if (t < 64) {
        const float a1 = P.bm1[t] + part[0][t] + part[1][t] + part[2][t] + part[3][t];
        hi1[t] = selu_f(a1);
    }
    __syncthreads();
    if (t < 64) {
        float a2 = P.bm2[t];
        #pragma unroll 8
        for (int k = 0; k < 64; ++k) a2 = fmaf(hi1[k], P.M2[k*64 + t], a2);
        hi2[t] = selu_f(a2);
    }
    __syncthreads();
    if (t < 128) {
        float a = P.bm3[t];
        #pragma unroll 8
        for (int k = 0; k < 64; ++k) a = fmaf(hi2[k], P.M3[k*128 + t], a);
        P.out1[r*128 + t] = a + P.feat[r*128 + t];
    } else if (t < 224) {
        const int o = t - 128;
        const int w = o / 3, c = o - w*3;
        float a = 0.f;
        #pragma unroll
        for (int v = 0; v < 32; ++v)
            a = fmaf(vecl[v*3 + c], P.Wmix[v*32 + w], a);
        P.out0[r*96 + o] = a + pos96[o];
    }
}

extern "C" void kernel_launch(void* const* d_in, const int* in_sizes, int n_in,
                              void* d_out, int out_size, void* d_ws, size_t ws_size,
                              hipStream_t stream)
{
    char* ws = (char*)d_ws;
    if (ws_size < (size_t)7024640) return;

    Params p;
    p.pos  = (const float*)d_in[0];
    p.feat = (const float*)d_in[1];
    p.We1  = (const float*)d_in[2];
    p.be1  = (const float*)d_in[3];
    p.We2  = (const float*)d_in[4];
    p.be2  = (const float*)d_in[5];
    p.Wq   = (const float*)d_in[6];
    p.Wk   = (const float*)d_in[7];
    p.Wv   = (const float*)d_in[8];
    p.Wvec = (const float*)d_in[9];
    p.Wmix = (const float*)d_in[10];
    p.M1   = (const float*)d_in[11];
    p.bm1  = (const float*)d_in[12];
    p.M2   = (const float*)d_in[13];
    p.bm2  = (const float*)d_in[14];
    p.M3   = (const float*)d_in[15];
    p.bm3  = (const float*)d_in[16];

    p.A    = (float*)(ws + 0);        // [256][64]
    p.Bf   = (float*)(ws + 65536);    // [256][64]
    p.kqb  = (u16*)(ws + 131072);     // [256][8][64]
    p.w1b  = (u16*)(ws + 393216);     // [64][256]
    p.we2b = (u16*)(ws + 425984);     // [64][64]
    p.wvb  = (u16*)(ws + 434176);     // [32][64]
    p.fvtH = (u16*)(ws + 438272);     // [128][256]
    p.fvtL = (u16*)(ws + 503808);
    p.ptH  = (u16*)(ws + 569344);     // [32][4][256]
    p.ptL  = (u16*)(ws + 634880);
    p.lgg2 = (float*)(ws + 700416);   // [256][8][256]
    p.cfg2 = (u16*)(ws + 2797568);    // [256][32][256]
    p.stats = (float*)(ws + 6991872); // [256][2][8][2]
    p.inv  = (float*)(ws + 0);        // overlay (A/Bf dead after K2)
    p.vec4 = (float*)(ws + 131072);   // overlay (kqb dead after K2)

    p.out0 = (float*)d_out;           // [256][32][3]
    p.out1 = p.out0 + NN*VC*3;        // [256][128]

    hipLaunchKernelGGL(k1_pre,  dim3(512), dim3(256), 0, stream, p);
    hipLaunchKernelGGL(k2_edge, dim3(512), dim3(256), 0, stream, p);
    hipLaunchKernelGGL(k3b_agg, dim3(640), dim3(64),  0, stream, p);
    hipLaunchKernelGGL(k3c_out, dim3(256), dim3(256), 0, stream, p);
}

// Round 12
// 44.252 us; speedup vs baseline: 1.0675x; 1.0300x over previous
//
#include <hip/hip_runtime.h>
#include <hip/hip_bf16.h>

#define NN 256
#define VC 32
#define FD 128

typedef unsigned int uint32;
typedef unsigned short u16;
typedef __attribute__((ext_vector_type(8))) short bf16x8;
typedef __attribute__((ext_vector_type(4))) float f32x4;

__device__ __forceinline__ float selu_f(float x) {
    const float lam = 1.0507009873554805f;
    const float la  = 1.7580993408473766f;
    return x > 0.f ? lam * x : la * (__expf(x) - 1.f);
}

__device__ __forceinline__ u16 f32_to_bf16_rne(float f) {
    uint32 u = __float_as_uint(f);
    uint32 r = (u + 0x7fffu + ((u >> 16) & 1u)) >> 16;
    return (u16)r;
}

__device__ __forceinline__ float bf16_to_f32(u16 h) {
    return __uint_as_float(((uint32)h) << 16);
}

struct Params {
    const float *pos, *feat, *We1, *be1, *We2, *be2, *Wq, *Wk, *Wv, *Wvec,
                *Wmix, *M1, *bm1, *M2, *bm2, *M3, *bm3;
    float *A, *Bf;
    u16 *kqb, *w1b, *we2b, *wvb, *fvtH, *fvtL, *ptH, *ptL;
    float *lgg2;
    u16 *cfg2;
    float *stats;            // [256 r][2 tpart][8 h][2] = (max, sumexp)
    float *invP, *vec4P;     // [2 kh][256][128] partials
    float *out0, *out1;
};

// ---------------------------------------------------------------- K1: node precompute (512 blocks)
__global__ __launch_bounds__(256) void k1_pre(Params P)
{
    __shared__ float fl[FD];
    __shared__ float ql[FD];
    const int vb = blockIdx.x;
    const int t = threadIdx.x;
    if (vb < 256) {
        const int n = vb;
        {   // weight repack spread (1 elem/thread over first 88 blocks)
            const int gid = n*256 + t;
            if (gid < 16384) {
                const int c = gid >> 8, k = gid & 255;
                P.w1b[gid] = f32_to_bf16_rne(P.We1[(256 + k)*64 + c]);
            } else if (gid < 20480) {
                const int o = gid - 16384;
                const int c = o >> 6, k = o & 63;
                P.we2b[o] = f32_to_bf16_rne(P.We2[k*64 + c]);
            } else if (gid < 22528) {
                const int o = gid - 20480;
                const int v = o >> 6, k = o & 63;
                P.wvb[o] = f32_to_bf16_rne(P.Wvec[k*32 + v]);
            }
        }
        if (t < FD) fl[t] = P.feat[n*FD + t];
        __syncthreads();
        if (t < 64) {
            float a = 0.f;
            for (int i = 0; i < FD; ++i) a = fmaf(fl[i], P.We1[i*64 + t], a);
            P.A[n*64 + t] = a;
        } else if (t < 128) {
            const int j = t - 64;
            float a = P.be1[j];
            for (int i = 0; i < FD; ++i) a = fmaf(fl[i], P.We1[(FD+i)*64 + j], a);
            P.Bf[n*64 + j] = a;
        } else {
            const int j = t - 128;
            float a = 0.f;
            for (int i = 0; i < FD; ++i) a = fmaf(fl[i], P.Wq[i*FD + j], a);
            ql[j] = a * 0.25f;   // fold 1/sqrt(DH)
        }
        if (t < 8)  P.lgg2[n*2048 + t*256 + n] = -1e30f;       // self-edge excluded
        if (t < 32) P.cfg2[(size_t)n*8192 + t*256 + n] = 0;
        __syncthreads();
        for (int o = t; o < 512; o += 256) {   // kqb[n][h][j]
            const int h = o >> 6, j = o & 63;
            float a = 0.f;
            #pragma unroll
            for (int d = 0; d < 16; ++d)
                a = fmaf(P.Wk[j*FD + h*16 + d], ql[h*16 + d], a);
            P.kqb[n*512 + o] = f32_to_bf16_rne(a);
        }
    } else {
        const int n = vb - 256;
        if (t < FD) fl[t] = P.feat[n*FD + t];
        __syncthreads();
        if (t < FD) {
            float a = 0.f;
            for (int i = 0; i < FD; ++i) a = fmaf(fl[i], P.Wv[i*FD + t], a);
            const u16 hi = f32_to_bf16_rne(a);
            const u16 lo = f32_to_bf16_rne(a - bf16_to_f32(hi));
            P.fvtH[t*256 + n] = hi;
            P.fvtL[t*256 + n] = lo;
            const int v = t >> 2, c = t & 3;
            const float val = (c < 3) ? P.pos[(n*VC + v)*3 + c] : 1.0f;
            const u16 phi = f32_to_bf16_rne(val);
            const u16 plo = f32_to_bf16_rne(val - bf16_to_f32(phi));
            P.ptH[(v*4+c)*256 + n] = phi;
            P.ptL[(v*4+c)*256 + n] = plo;
        }
    }
}

// ---------------------------------------------------------------- K2: edge pipeline (MFMA) + softmax partials, 512 blocks
__global__ __launch_bounds__(256) void k2_edge(Params P)
{
    __shared__ u16 rad[8192];       // [32e][32v][8b] bf16, xor-swizzled (16KB)
    __shared__ u16 h1b[2048];
    __shared__ u16 h2b[2048];
    __shared__ float invl[1056];
    __shared__ float pm[2][8];      // softmax partial max  [eh][h]
    __shared__ float psv[2][8];     // softmax partial sum  [eh][h]

    const int t = threadIdx.x;
    const int wave = t >> 6, l = t & 63;
    const int li = l & 15, q = l >> 4;
    const int mh = wave >> 1, eh = wave & 1;
    const int r = blockIdx.x >> 1, tpart = blockIdx.x & 1;
    const int e = eh*16 + li;
    const int swz16 = (e & 7) << 3;

    bf16x8 w1A[2][8];
    #pragma unroll
    for (int mt = 0; mt < 2; ++mt) {
        const int c = mh*32 + mt*16 + li;
        #pragma unroll
        for (int kb = 0; kb < 8; ++kb)
            w1A[mt][kb] = *(const bf16x8*)(P.w1b + c*256 + kb*32 + q*8);
    }
    bf16x8 we2A[2][2];
    #pragma unroll
    for (int mt = 0; mt < 2; ++mt) {
        const int c2 = mh*32 + mt*16 + li;
        #pragma unroll
        for (int kb = 0; kb < 2; ++kb)
            we2A[mt][kb] = *(const bf16x8*)(P.we2b + c2*64 + kb*32 + q*8);
    }
    bf16x8 wvA[2];
    {
        const int v = mh*16 + li;
        #pragma unroll
        for (int kb = 0; kb < 2; ++kb)
            wvA[kb] = *(const bf16x8*)(P.wvb + v*64 + kb*32 + q*8);
    }
    bf16x8 kqA[2];
    if (li < 8) {
        #pragma unroll
        for (int kb = 0; kb < 2; ++kb)
            kqA[kb] = *(const bf16x8*)(P.kqb + r*512 + li*64 + kb*32 + q*8);
    } else {
        #pragma unroll
        for (int kb = 0; kb < 2; ++kb)
            #pragma unroll
            for (int j = 0; j < 8; ++j) kqA[kb][j] = 0;
    }
    float bfreg[2][4], be2reg[2][4];
    #pragma unroll
    for (int mt = 0; mt < 2; ++mt)
        #pragma unroll
        for (int rg = 0; rg < 4; ++rg) {
            const int c = mh*32 + mt*16 + q*4 + rg;
            bfreg[mt][rg] = P.Bf[r*64 + c];
            be2reg[mt][rg] = P.be2[c];
        }

    float m_run[4], s_run[4];
    #pragma unroll
    for (int rg = 0; rg < 4; ++rg) { m_run[rg] = -3.0e38f; s_run[rg] = 0.f; }

    for (int it = 0; it < 4; ++it) {
        const int s0 = (tpart*4 + it) * 32;
        const int sp = s0 + e;
        int s = sp + (sp >= r ? 1 : 0); if (s > 255) s = 255;
        __syncthreads();

        float As[2][4];
        #pragma unroll
        for (int mt = 0; mt < 2; ++mt)
            #pragma unroll
            for (int rg = 0; rg < 4; ++rg)
                As[mt][rg] = P.A[s*64 + mh*32 + mt*16 + q*4 + rg];

        {   // radial basis -> swizzled LDS
            const int ep = t & 31, vg = t >> 5;
            const int spp = s0 + ep;
            int sv = spp + (spp >= r ? 1 : 0); if (sv > 255) sv = 255;
            #pragma unroll
            for (int kk = 0; kk < 4; ++kk) {
                const int v = vg*4 + kk;
                const float* ps = P.pos + (sv*VC + v)*3;
                const float* pr = P.pos + (r*VC + v)*3;
                const float dx = ps[0]-pr[0], dy = ps[1]-pr[1], dz = ps[2]-pr[2];
                const float d2 = fmaf(dx,dx,fmaf(dy,dy,dz*dz)) + 1e-18f;
                const float len = sqrtf(d2);
                invl[ep*33 + v] = rsqrtf(d2);
                const float x = fmaxf(len, 1e-6f);
                const float tt2 = 2.f - 0.4f*len;
                const float env = tt2 > 0.f ? 1.9784655248401538f * __expf(-1.f/tt2) : 0.f;
                const float coefc = 0.6324555320336759f * env / x;
                float s_cur, c1;
                __sincosf(0.6283185307179586f * x, &s_cur, &c1);
                const float c2x = 2.f * c1;
                float s_prev = 0.f;
                union { uint4 u4; u16 us[8]; } pk;
                #pragma unroll
                for (int bb = 0; bb < 8; ++bb) {
                    pk.us[bb] = f32_to_bf16_rne(coefc * s_cur);
                    const float s_next = fmaf(c2x, s_cur, -s_prev);
                    s_prev = s_cur; s_cur = s_next;
                }
                *(uint4*)((char*)rad + ((ep*512 + v*16) ^ ((ep & 15) << 4))) = pk.u4;
            }
        }
        __syncthreads();

        f32x4 d1[2] = {{0.f,0.f,0.f,0.f},{0.f,0.f,0.f,0.f}};
        #pragma unroll
        for (int kb = 0; kb < 8; ++kb) {
            const bf16x8 rf = *(const bf16x8*)((const char*)rad +
                                ((e*512 + (kb*4+q)*16) ^ ((e & 15) << 4)));
            d1[0] = __builtin_amdgcn_mfma_f32_16x16x32_bf16(w1A[0][kb], rf, d1[0], 0, 0, 0);
            d1[1] = __builtin_amdgcn_mfma_f32_16x16x32_bf16(w1A[1][kb], rf, d1[1], 0, 0, 0);
        }
        #pragma unroll
        for (int mt = 0; mt < 2; ++mt) {
            const int c0 = mh*32 + mt*16 + q*4;
            const u16 p0 = f32_to_bf16_rne(selu_f(d1[mt][0] + As[mt][0] + bfreg[mt][0]));
            const u16 p1 = f32_to_bf16_rne(selu_f(d1[mt][1] + As[mt][1] + bfreg[mt][1]));
            const u16 p2 = f32_to_bf16_rne(selu_f(d1[mt][2] + As[mt][2] + bfreg[mt][2]));
            const u16 p3 = f32_to_bf16_rne(selu_f(d1[mt][3] + As[mt][3] + bfreg[mt][3]));
            *(uint32*)&h1b[e*64 + ((c0)     ^ swz16)] = (uint32)p0 | ((uint32)p1 << 16);
            *(uint32*)&h1b[e*64 + ((c0 + 2) ^ swz16)] = (uint32)p2 | ((uint32)p3 << 16);
        }
        __syncthreads();

        f32x4 d2[2] = {{0.f,0.f,0.f,0.f},{0.f,0.f,0.f,0.f}};
        #pragma unroll
        for (int kb = 0; kb < 2; ++kb) {
            const bf16x8 hb = *(const bf16x8*)&h1b[e*64 + ((kb*32 + q*8) ^ swz16)];
            d2[0] = __builtin_amdgcn_mfma_f32_16x16x32_bf16(we2A[0][kb], hb, d2[0], 0, 0, 0);
            d2[1] = __builtin_amdgcn_mfma_f32_16x16x32_bf16(we2A[1][kb], hb, d2[1], 0, 0, 0);
        }
        #pragma unroll
        for (int mt = 0; mt < 2; ++mt) {
            const int c0 = mh*32 + mt*16 + q*4;
            const u16 p0 = f32_to_bf16_rne(selu_f(d2[mt][0] + be2reg[mt][0]));
            const u16 p1 = f32_to_bf16_rne(selu_f(d2[mt][1] + be2reg[mt][1]));
            const u16 p2 = f32_to_bf16_rne(selu_f(d2[mt][2] + be2reg[mt][2]));
            const u16 p3 = f32_to_bf16_rne(selu_f(d2[mt][3] + be2reg[mt][3]));
            *(uint32*)&h2b[e*64 + ((c0)     ^ swz16)] = (uint32)p0 | ((uint32)p1 << 16);
            *(uint32*)&h2b[e*64 + ((c0 + 2) ^ swz16)] = (uint32)p2 | ((uint32)p3 << 16);
        }
        __syncthreads();

        f32x4 d3 = {0.f,0.f,0.f,0.f};
        f32x4 dl = {0.f,0.f,0.f,0.f};
        #pragma unroll
        for (int kb = 0; kb < 2; ++kb) {
            const bf16x8 hb = *(const bf16x8*)&h2b[e*64 + ((kb*32 + q*8) ^ swz16)];
            d3 = __builtin_amdgcn_mfma_f32_16x16x32_bf16(wvA[kb], hb, d3, 0, 0, 0);
            if (mh == 0)
                dl = __builtin_amdgcn_mfma_f32_16x16x32_bf16(kqA[kb], hb, dl, 0, 0, 0);
        }
        if (sp < 255) {
            #pragma unroll
            for (int rg = 0; rg < 4; ++rg) {
                const int v = mh*16 + q*4 + rg;
                P.cfg2[(size_t)r*8192 + v*256 + s] =
                    f32_to_bf16_rne(d3[rg] * 1.7320508075688772f * invl[e*33 + v]);
            }
            if (mh == 0 && q < 2) {
                #pragma unroll
                for (int rg = 0; rg < 4; ++rg) {
                    const float lgv = dl[rg];
                    P.lgg2[(size_t)r*2048 + (q*4+rg)*256 + s] = lgv;
                    const float mo = m_run[rg];
                    if (lgv > mo) {
                        s_run[rg] = fmaf(s_run[rg], __expf(mo - lgv), 1.f);
                        m_run[rg] = lgv;
                    } else {
                        s_run[rg] += __expf(lgv - mo);
                    }
                }
            }
        }
    }

    // ---- combine softmax partials: reduce over li (in-wave), then over eh (LDS)
    if (mh == 0 && q < 2) {
        #pragma unroll
        for (int rg = 0; rg < 4; ++rg) {
            float m = m_run[rg], sv = s_run[rg];
            #pragma unroll
            for (int mask = 1; mask <= 8; mask <<= 1) {
                const float mo = __shfl_xor(m, mask);
                const float so = __shfl_xor(sv, mask);
                const float mn = fmaxf(m, mo);
                sv = sv*__expf(m - mn) + so*__expf(mo - mn);
                m = mn;
            }
            if (li == 0) { pm[eh][q*4+rg] = m; psv[eh][q*4+rg] = sv; }
        }
    }
    __syncthreads();
    if (t < 8) {
        const float m0 = pm[0][t], m1 = pm[1][t];
        const float s0v = psv[0][t], s1v = psv[1][t];
        const float m = fmaxf(m0, m1);
        const float sv = s0v*__expf(m0 - m) + s1v*__expf(m1 - m);
        P.stats[((r*2 + tpart)*8 + t)*2 + 0] = m;
        P.stats[((r*2 + tpart)*8 + t)*2 + 1] = sv;
    }
}

// ---------------------------------------------------------------- K3b: MFMA aggregations, K-split x2 (1280 x 64)
// blockIdx = task*2 + kh; kh selects sender half (kb = kh*4 .. kh*4+4).
__global__ __launch_bounds__(64) void k3b_agg(Params P)
{
    const int l = threadIdx.x, li = l & 15, q = l >> 4;
    const int kh = blockIdx.x & 1;
    const int task = blockIdx.x >> 1;
    const int kb0 = kh * 4;
    int r0, hh, v = 0;
    const bool isInv = (task < 128);
    if (isInv) { hh = task >> 4; r0 = (task & 15) * 16; }
    else { const int b2 = task - 128; v = b2 >> 4; r0 = (b2 & 15) * 16; hh = v >> 2; }

    // per-row softmax constants from k2 partials (row = r0+li)
    const float2 st0 = *(const float2*)&P.stats[(((r0+li)*2 + 0)*8 + hh)*2];
    const float2 st1 = *(const float2*)&P.stats[(((r0+li)*2 + 1)*8 + hh)*2];
    const float mx = fmaxf(st0.x, st1.x);
    const float den = st0.y*__expf(st0.x - mx) + st1.y*__expf(st1.x - mx);
    const float invden = 1.f / (den + 1e-12f);
    float* outP = (isInv ? P.invP : P.vec4P) + kh*32768;

    if (isInv) {
        bf16x8 fH[4], fL[4];
        #pragma unroll
        for (int k = 0; k < 4; ++k) {
            fH[k] = *(const bf16x8*)(P.fvtH + (hh*16+li)*256 + (kb0+k)*32 + q*8);
            fL[k] = *(const bf16x8*)(P.fvtL + (hh*16+li)*256 + (kb0+k)*32 + q*8);
        }
        const float* lgr = P.lgg2 + (size_t)(r0+li)*2048 + hh*256;
        f32x4 Ch = {0.f,0.f,0.f,0.f};
        f32x4 Cl = {0.f,0.f,0.f,0.f};
        #pragma unroll
        for (int k = 0; k < 4; ++k) {
            const float4 g0 = *(const float4*)(lgr + (kb0+k)*32 + q*8);
            const float4 g1 = *(const float4*)(lgr + (kb0+k)*32 + q*8 + 4);
            bf16x8 a;
            a[0] = (short)f32_to_bf16_rne(__expf(g0.x-mx));
            a[1] = (short)f32_to_bf16_rne(__expf(g0.y-mx));
            a[2] = (short)f32_to_bf16_rne(__expf(g0.z-mx));
            a[3] = (short)f32_to_bf16_rne(__expf(g0.w-mx));
            a[4] = (short)f32_to_bf16_rne(__expf(g1.x-mx));
            a[5] = (short)f32_to_bf16_rne(__expf(g1.y-mx));
            a[6] = (short)f32_to_bf16_rne(__expf(g1.z-mx));
            a[7] = (short)f32_to_bf16_rne(__expf(g1.w-mx));
            Ch = __builtin_amdgcn_mfma_f32_16x16x32_bf16(a, fH[k], Ch, 0, 0, 0);
            Cl = __builtin_amdgcn_mfma_f32_16x16x32_bf16(a, fL[k], Cl, 0, 0, 0);
        }
        #pragma unroll
        for (int rg = 0; rg < 4; ++rg) {
            const float d = __shfl(invden, q*4 + rg);
            outP[(r0 + q*4 + rg)*128 + hh*16 + li] = (Ch[rg] + Cl[rg]) * d;
        }
    } else {
        bf16x8 pH[4], pL[4];
        #pragma unroll
        for (int k = 0; k < 4; ++k) {
            if (li < 4) {
                pH[k] = *(const bf16x8*)(P.ptH + (v*4+li)*256 + (kb0+k)*32 + q*8);
                pL[k] = *(const bf16x8*)(P.ptL + (v*4+li)*256 + (kb0+k)*32 + q*8);
            } else {
                #pragma unroll
                for (int j = 0; j < 8; ++j) { pH[k][j] = 0; pL[k][j] = 0; }
            }
        }
        const float* lgr = P.lgg2 + (size_t)(r0+li)*2048 + hh*256;
        const u16*  cfr = P.cfg2 + (size_t)(r0+li)*8192 + v*256;
        f32x4 Ch = {0.f,0.f,0.f,0.f};
        f32x4 Cl = {0.f,0.f,0.f,0.f};
        #pragma unroll
        for (int k = 0; k < 4; ++k) {
            const float4 g0 = *(const float4*)(lgr + (kb0+k)*32 + q*8);
            const float4 g1 = *(const float4*)(lgr + (kb0+k)*32 + q*8 + 4);
            const bf16x8 cf8 = *(const bf16x8*)(cfr + (kb0+k)*32 + q*8);
            bf16x8 a;
            a[0] = (short)f32_to_bf16_rne(__expf(g0.x-mx) * bf16_to_f32((u16)cf8[0]));
            a[1] = (short)f32_to_bf16_rne(__expf(g0.y-mx) * bf16_to_f32((u16)cf8[1]));
            a[2] = (short)f32_to_bf16_rne(__expf(g0.z-mx) * bf16_to_f32((u16)cf8[2]));
            a[3] = (short)f32_to_bf16_rne(__expf(g0.w-mx) * bf16_to_f32((u16)cf8[3]));
            a[4] = (short)f32_to_bf16_rne(__expf(g1.x-mx) * bf16_to_f32((u16)cf8[4]));
            a[5] = (short)f32_to_bf16_rne(__expf(g1.y-mx) * bf16_to_f32((u16)cf8[5]));
            a[6] = (short)f32_to_bf16_rne(__expf(g1.z-mx) * bf16_to_f32((u16)cf8[6]));
            a[7] = (short)f32_to_bf16_rne(__expf(g1.w-mx) * bf16_to_f32((u16)cf8[7]));
            Ch = __builtin_amdgcn_mfma_f32_16x16x32_bf16(a, pH[k], Ch, 0, 0, 0);
            Cl = __builtin_amdgcn_mfma_f32_16x16x32_bf16(a, pL[k], Cl, 0, 0, 0);
        }
        #pragma unroll
        for (int rg = 0; rg < 4; ++rg) {
            const float d = __shfl(invden, q*4 + rg);
            if (li < 4)
                outP[(r0 + q*4 + rg)*128 + v*4 + li] = (Ch[rg] + Cl[rg]) * d;
        }
    }
}

// ---------------------------------------------------------------- K3c: node MLP + vec combine (1 node/block, 256 thr)
__global__ __launch_bounds__(256) void k3c_out(Params P)
{
    __shared__ float part[4][64];
    __shared__ float inva[128];
    __shared__ float vec4s[128];
    __shared__ float pos96[96];
    __shared__ float vecl[96];
    __shared__ float hi1[64];
    __shared__ float hi2[64];
    const int r = blockIdx.x;
    const int t = threadIdx.x;
    if (t < 128) inva[t] = P.invP[r*128 + t] + P.invP[32768 + r*128 + t];
    else {
        const int o = t - 128;
        vec4s[o] = P.vec4P[r*128 + o] + P.vec4P[32768 + r*128 + o];
    }
    if (t < 96)  pos96[t] = P.pos[r*96 + t];
    __syncthreads();
    if (t < 96) {
        const int v = t / 3, c = t - v*3;
        vecl[t] = vec4s[v*4 + c] - vec4s[v*4 + 3] * pos96[t];
    }
    {   // stage1 partials: 4-way K-split
        const int f = t & 63, g = t >> 6;
        const int k0 = g*32;
        float acc = 0.f;
        #pragma unroll 8
        for (int k = k0; k < k0 + 32; ++k)
            acc = fmaf(inva[k], P.M1[k*64 + f], acc);
        part[g][f] = acc;
    }
    __syncthreads();
    if (t < 64) {
        const float a1 = P.bm1[t] + part[0][t] + part[1][t] + part[2][t] + part[3][t];
        hi1[t] = selu_f(a1);
    }
    __syncthreads();
    if (t < 64) {
        float a2 = P.bm2[t];
        #pragma unroll 8
        for (int k = 0; k < 64; ++k) a2 = fmaf(hi1[k], P.M2[k*64 + t], a2);
        hi2[t] = selu_f(a2);
    }
    __syncthreads();
    if (t < 128) {
        float a = P.bm3[t];
        #pragma unroll 8
        for (int k = 0; k < 64; ++k) a = fmaf(hi2[k], P.M3[k*128 + t], a);
        P.out1[r*128 + t] = a + P.feat[r*128 + t];
    } else if (t < 224) {
        const int o = t - 128;
        const int w = o / 3, c = o - w*3;
        float a = 0.f;
        #pragma unroll
        for (int v = 0; v < 32; ++v)
            a = fmaf(vecl[v*3 + c], P.Wmix[v*32 + w], a);
        P.out0[r*96 + o] = a + pos96[o];
    }
}

extern "C" void kernel_launch(void* const* d_in, const int* in_sizes, int n_in,
                              void* d_out, int out_size, void* d_ws, size_t ws_size,
                              hipStream_t stream)
{
    char* ws = (char*)d_ws;
    if (ws_size < (size_t)7532544) return;

    Params p;
    p.pos  = (const float*)d_in[0];
    p.feat = (const float*)d_in[1];
    p.We1  = (const float*)d_in[2];
    p.be1  = (const float*)d_in[3];
    p.We2  = (const float*)d_in[4];
    p.be2  = (const float*)d_in[5];
    p.Wq   = (const float*)d_in[6];
    p.Wk   = (const float*)d_in[7];
    p.Wv   = (const float*)d_in[8];
    p.Wvec = (const float*)d_in[9];
    p.Wmix = (const float*)d_in[10];
    p.M1   = (const float*)d_in[11];
    p.bm1  = (const float*)d_in[12];
    p.M2   = (const float*)d_in[13];
    p.bm2  = (const float*)d_in[14];
    p.M3   = (const float*)d_in[15];
    p.bm3  = (const float*)d_in[16];

    p.A    = (float*)(ws + 0);        // [256][64]
    p.Bf   = (float*)(ws + 65536);    // [256][64]
    p.kqb  = (u16*)(ws + 131072);     // [256][8][64]
    p.w1b  = (u16*)(ws + 393216);     // [64][256]
    p.we2b = (u16*)(ws + 425984);     // [64][64]
    p.wvb  = (u16*)(ws + 434176);     // [32][64]
    p.fvtH = (u16*)(ws + 438272);     // [128][256]
    p.fvtL = (u16*)(ws + 503808);
    p.ptH  = (u16*)(ws + 569344);     // [32][4][256]
    p.ptL  = (u16*)(ws + 634880);
    p.lgg2 = (float*)(ws + 700416);   // [256][8][256]
    p.cfg2 = (u16*)(ws + 2797568);    // [256][32][256]
    p.stats = (float*)(ws + 6991872); // [256][2][8][2]
    p.invP  = (float*)(ws + 7008256); // [2][256][128]
    p.vec4P = (float*)(ws + 7270400); // [2][256][128]

    p.out0 = (float*)d_out;           // [256][32][3]
    p.out1 = p.out0 + NN*VC*3;        // [256][128]

    hipLaunchKernelGGL(k1_pre,  dim3(512),  dim3(256), 0, stream, p);
    hipLaunchKernelGGL(k2_edge, dim3(512),  dim3(256), 0, stream, p);
    hipLaunchKernelGGL(k3b_agg, dim3(1280), dim3(64),  0, stream, p);
    hipLaunchKernelGGL(k3c_out, dim3(256),  dim3(256), 0, stream, p);
}